// Round 5
// baseline (91.227 us; speedup 1.0000x reference)
//
#include <hip/hip_runtime.h>

// log2-domain "log 0": exp2(-30000) == 0, exactly representable in half, never NaN.
#define NEG2 (-30000.0f)
#define L2E  1.4426950408889634f
#define LN2  0.6931471805599453f

constexpr int B = 8, T = 128, U = 64, U1 = 65, V = 512;

// workspace layout (float units)
constexpr int ETH_F = 0;                            // exp(trans-mt) f16: B*T*V halves
constexpr int EPH_F = ETH_F + (B * T * V) / 2;      // exp(pred-mp) f16: B*U1*V halves
constexpr int MT_F  = EPH_F + (B * U1 * V) / 2;     // row max trans: B*T f32
constexpr int MP_F  = MT_F + B * T;                 // row max pred:  B*U1 f32
constexpr int T0_F  = MP_F + B * U1;                // trans[.,0]: B*T f32
constexpr int P0_F  = T0_F + B * T;                 // pred[.,0]:  B*U1 f32
constexpr int PL_F  = P0_F + B * U1;                // pred[u][labels[u]]: B*U1 f32
constexpr int TL_F  = PL_F + B * U1;                // trans[t][labels[u]] f16: B*T*64 halves

typedef _Float16 half_t;
typedef _Float16 v4h __attribute__((ext_vector_type(4)));
typedef _Float16 v8h __attribute__((ext_vector_type(8)));
typedef float    v4f __attribute__((ext_vector_type(4)));

__device__ __forceinline__ float wave_shr1(float x) {  // lane i <- lane i-1 (lane0 keeps own)
    int v = __float_as_int(x);
    int r = __builtin_amdgcn_update_dpp(v, v, 0x138, 0xF, 0xF, false); // wave_shr:1
    return __int_as_float(r);
}

// ---------------- k1: row max + exp (f16 out) + gather precomputes + zero out ----------------
__global__ __launch_bounds__(256) void k_prep(const float* __restrict__ trans,
                                              const float* __restrict__ pred,
                                              const int* __restrict__ labels,
                                              float* __restrict__ ws,
                                              float* __restrict__ out) {
    if (blockIdx.x == 0 && threadIdx.x == 0) out[0] = 0.0f;
    const int wave = (blockIdx.x * blockDim.x + threadIdx.x) >> 6;
    const int lane = threadIdx.x & 63;
    const int nrows_t = B * T;              // 1024 trans rows
    const int nrows = nrows_t + B * U1;     // + 520 pred rows
    if (wave >= nrows) return;

    const float* src; half_t* dst;
    if (wave < nrows_t) {
        src = trans + (size_t)wave * V;
        dst = (half_t*)(ws + ETH_F) + (size_t)wave * V;
    } else {
        const int r = wave - nrows_t;
        src = pred + (size_t)r * V;
        dst = (half_t*)(ws + EPH_F) + (size_t)r * V;
    }

    const float4 a = ((const float4*)src)[lane];
    const float4 c = ((const float4*)src)[lane + 64];
    float m = fmaxf(fmaxf(fmaxf(a.x, a.y), fmaxf(a.z, a.w)),
                    fmaxf(fmaxf(c.x, c.y), fmaxf(c.z, c.w)));
    #pragma unroll
    for (int off = 32; off >= 1; off >>= 1) m = fmaxf(m, __shfl_xor(m, off));

    v4h h0 = { (half_t)__expf(a.x - m), (half_t)__expf(a.y - m),
               (half_t)__expf(a.z - m), (half_t)__expf(a.w - m) };
    v4h h1 = { (half_t)__expf(c.x - m), (half_t)__expf(c.y - m),
               (half_t)__expf(c.z - m), (half_t)__expf(c.w - m) };
    ((v4h*)dst)[lane]      = h0;
    ((v4h*)dst)[lane + 64] = h1;

    if (wave < nrows_t) {                   // trans row (b,t)
        const int b = wave >> 7;
        const int lbl = labels[b * U + lane];                 // lane == u, U==64
        ((half_t*)(ws + TL_F))[(size_t)wave * 64 + lane] = (half_t)src[lbl];
        if (lane == 0) { ws[MT_F + wave] = m; ws[T0_F + wave] = a.x; }
    } else {                                // pred row (b,u)
        const int r = wave - nrows_t;
        if (lane == 0) {
            const int b = r / U1, u = r % U1;
            ws[MP_F + r] = m; ws[P0_F + r] = a.x;
            if (u < U) ws[PL_F + r] = src[labels[b * U + u]];
        }
    }
}

// ---------------- k2: fused joint GEMM + epilogue-to-LDS + anti-diagonal DP (v3) ----------------
// One block per b (8 x 512), launch_bounds(512,2) => 256-VGPR budget (round-2 fix).
// Wave w = t-tile w. A-frags: named unrolled register array, loaded ONCE (64 VGPR).
// B-tile: staged in LDS per u-tile, shared by all 8 waves (8x less global B traffic than
// round-3's per-wave reloads — that was 160 serialized loads/wave = 45 us). XOR swizzle
// (cp ^ (n&7)) applied on BOTH stage-write and frag-read spreads ds_read_b128 banks.
// Lattice is born in LDS (row idx = lattice row d-1, same as verified round-1 staging).
__global__ __launch_bounds__(512, 2) void k_joint_dp(const int* __restrict__ label_lens,
                                                     const int* __restrict__ act_lens,
                                                     const float* __restrict__ ws,
                                                     float* __restrict__ out) {
    const int b = blockIdx.x;
    const int tid = threadIdx.x;
    const int w = tid >> 6;                  // wave = t-tile 0..7
    const int lane = tid & 63;
    const int n = lane & 15, q = lane >> 4;

    constexpr int DROWS = 192;               // lattice rows 1..192 at idx d-1
    __shared__ uint Lat[DROWS * 64];                 // 48 KB
    __shared__ __align__(16) half_t BsH[16 * 512];   // 16 KB B-tile (swizzled chunks)
    __shared__ float c0s[T];                 // blank~[t][0] column
    __shared__ float af[T];                  // alpha~[t][0] column

    const int t0 = w * 16;
    const int ul = label_lens[b];

    // ---- A-frags: named unrolled register array, loaded once (static indices only) ----
    const v8h* A = (const v8h*)((const half_t*)(ws + ETH_F) + ((size_t)(b * T + t0 + n)) * V);
    v8h areg[16];
    #pragma unroll
    for (int c = 0; c < 16; ++c) areg[c] = A[c * 4 + q];

    // per-t epilogue scalars (same t rows for all 5 u-tiles) hoisted
    float mt_i[4], t0v[4];
    #pragma unroll
    for (int i = 0; i < 4; ++i) {
        const int t = t0 + q * 4 + i;
        mt_i[i] = ws[MT_F + b * T + t];
        t0v[i]  = ws[T0_F + b * T + t];
    }
    const half_t* TLh  = (const half_t*)(ws + TL_F) + (size_t)(b * T) * 64;
    const half_t* EPHb = (const half_t*)(ws + EPH_F) + (size_t)b * U1 * V;
    half_t* LatH = (half_t*)Lat;

    #pragma unroll 1
    for (int j = 0; j < 5; ++j) {            // u-tiles
        const int u0 = j * 16;

        // ---- stage B-tile j into LDS (2 x 16B chunks per thread, swizzled source) ----
        // physical chunk (n, cp) holds logical chunk (n, cp ^ (n&7)); row clamped to 64.
        v8h rA, rB;
        {
            const int c0i = tid,       n0 = c0i >> 6, cp0 = c0i & 63;
            const int c1i = tid + 512, n1 = c1i >> 6, cp1 = c1i & 63;
            const int r0 = (u0 + n0 <= 64) ? (u0 + n0) : 64;
            const int r1 = (u0 + n1 <= 64) ? (u0 + n1) : 64;
            rA = *(const v8h*)(EPHb + (size_t)r0 * V + (cp0 ^ (n0 & 7)) * 8);
            rB = *(const v8h*)(EPHb + (size_t)r1 * V + (cp1 ^ (n1 & 7)) * 8);
        }
        __syncthreads();                     // prev-tile LDS reads done
        ((v8h*)BsH)[tid]       = rA;
        ((v8h*)BsH)[tid + 512] = rB;
        __syncthreads();                     // tile j visible to all waves

        // ---- B-frags from LDS (swizzled read = same involution) ----
        v8h breg[16];
        #pragma unroll
        for (int c = 0; c < 16; ++c) {
            const int k = c * 4 + q;
            breg[c] = *(const v8h*)(BsH + n * 512 + ((k ^ (n & 7)) * 8));
        }

        v4f acc = {0.f, 0.f, 0.f, 0.f};
        #pragma unroll
        for (int c = 0; c < 16; ++c)         // 16 MFMAs, K=512 (same order as verified)
            acc = __builtin_amdgcn_mfma_f32_16x16x32_f16(areg[c], breg[c], acc, 0, 0, 0);

        // ---- epilogue: C/D col = lane&15 (-> u), row = q*4 + i (-> t); into LDS lattice ----
        const int u = u0 + n;
        if (u <= 64) {
            const float mp_u = ws[MP_F + b * U1 + u];
            const float pr0  = ws[P0_F + b * U1 + u];
            const bool has_lab = (u < 64);
            const float prl = has_lab ? ws[PL_F + b * U1 + u] : 0.f;
            #pragma unroll
            for (int i = 0; i < 4; ++i) {
                const int t = t0 + q * 4 + i;
                const float lse2 = (mt_i[i] + mp_u) * L2E + __log2f(acc[i]);
                const float bl2 = (t0v[i] + pr0) * L2E - lse2;   // blank~[t][u]
                const int d = t + u + 1;                         // lattice row; idx = d-1
                if (u >= 1) LatH[((d - 1) * 64 + (u - 1)) * 2] = (half_t)bl2;
                else        c0s[t] = bl2;
                if (has_lab) {
                    const float lb2 = (u >= ul) ? NEG2
                                     : ((float)TLh[t * 64 + u] + prl) * L2E - lse2;  // lab~[t][u]
                    LatH[((d - 1) * 64 + u) * 2 + 1] = (half_t)lb2;
                }
            }
        }
    }
    __syncthreads();                         // lattice + c0 complete in LDS
    if (w != 0) return;

    // ---- DP: wave 0, lane l owns u = l+1; at step d, t = d-l-1 ----
    const int l = lane;

    // alpha0 column: inclusive prefix scan of c0s (128 values, 2 per lane)
    float x0 = c0s[l], x1 = c0s[64 + l];
    #pragma unroll
    for (int off = 1; off < 64; off <<= 1) { float y = __shfl_up(x0, off); if (l >= off) x0 += y; }
    #pragma unroll
    for (int off = 1; off < 64; off <<= 1) { float y = __shfl_up(x1, off); if (l >= off) x1 += y; }
    const float tot = __shfl(x0, 63);
    if (l == 0) af[0] = 0.0f;
    af[l + 1] = x0;                          // t = 1..64
    if (l < 63) af[65 + l] = tot + x1;       // t = 65..127

    const int tl = act_lens[b] - 1;          // >= 63
    const int dmaxp1 = tl + ul + 1;          // <= 192

    // depth-4 prefetch with NAMED registers — immune to unroll heuristics (rule #20)
    uint  w0 = Lat[0 * 64 + l], w1 = Lat[1 * 64 + l], w2 = Lat[2 * 64 + l], w3 = Lat[3 * 64 + l];
    float a0 = af[0],           a1r = af[1],          a2r = af[2],          a3r = af[3];

    float cur = 0.0f;

#define DP_STEP(DD, WREG, AREG)                                                    \
    do {                                                                           \
        const int dd = (DD);                                                       \
        const int t = dd - l - 1;                                                  \
        union { uint u; half_t h[2]; } cv; cv.u = WREG;                            \
        const float bn = (float)cv.h[0];     /* blank~[t-1][u] */                  \
        const float lb = (float)cv.h[1];     /* lab~[t][u-1]   */                  \
        const float sh = wave_shr1(cur);                                           \
        const float lv = (l == 0) ? AREG : sh;  /* alpha[t][u-1] */                \
        const float a2v = lv + lb;                                                 \
        const float a1v = (t >= 1) ? cur + bn : NEG2;                              \
        const float mx = fmaxf(a1v, a2v);                                          \
        const float nc = mx + __log2f(1.0f + exp2f(-fabsf(a1v - a2v)));            \
        cur = ((t >= 0) && (t <= tl)) ? nc : cur;                                  \
        const int pr = (dd + 3 < DROWS) ? dd + 3 : DROWS - 1;                      \
        WREG = Lat[pr * 64 + l];                                                   \
        AREG = af[(dd + 3 < T) ? dd + 3 : T - 1];                                  \
    } while (0)

    for (int d4 = 1; d4 <= 189; d4 += 4) {   // 48 groups cover d = 1..192
        DP_STEP(d4 + 0, w0, a0);
        DP_STEP(d4 + 1, w1, a1r);
        DP_STEP(d4 + 2, w2, a2r);
        DP_STEP(d4 + 3, w3, a3r);
    }
#undef DP_STEP

    if (l == ul - 1) {                       // cur == alpha~[tl][ul]
        union { uint u; half_t h[2]; } cv; cv.u = Lat[(dmaxp1 - 1) * 64 + (ul - 1)];
        atomicAdd(out, -((cur + (float)cv.h[0]) * LN2));
    }
}

extern "C" void kernel_launch(void* const* d_in, const int* in_sizes, int n_in,
                              void* d_out, int out_size, void* d_ws, size_t ws_size,
                              hipStream_t stream) {
    const float* trans      = (const float*)d_in[0];
    const float* pred       = (const float*)d_in[1];
    const int*   labels     = (const int*)d_in[2];
    const int*   act_lens   = (const int*)d_in[3];
    const int*   label_lens = (const int*)d_in[4];
    float* ws  = (float*)d_ws;
    float* out = (float*)d_out;

    const int nrows = B * T + B * U1;                       // 1544 waves
    k_prep<<<(nrows + 3) / 4, 256, 0, stream>>>(trans, pred, labels, ws, out);
    k_joint_dp<<<8, 512, 0, stream>>>(label_lens, act_lens, ws, out);
}